// Round 13
// baseline (160.057 us; speedup 1.0000x reference)
//
#include <hip/hip_runtime.h>

typedef __bf16 bf16x8 __attribute__((ext_vector_type(8)));
typedef float  f32x4  __attribute__((ext_vector_type(4)));

struct KArgs {
    const float* x[6];
    const float* W[6];
    const float* b[6];
    float*       out[6];
    int nrows[6];
    int blk0[7];
};

// producer: counted load-only wait fused with barrier (queue has ONLY DMAs).
// Depth-3: wait until <=8 outstanding => oldest chunk fully landed.
__device__ __forceinline__ void prod_wait_bar() {
    asm volatile("s_waitcnt vmcnt(8)\n\ts_barrier" ::: "memory");
}
// consumer: lgkm-only barrier (its vmem queue = stores; never waited)
__device__ __forceinline__ void cons_bar() {
    asm volatile("s_waitcnt lgkmcnt(0)\n\ts_barrier" ::: "memory");
}

__device__ __forceinline__ void gload_lds16(const float* g, void* l) {
    __builtin_amdgcn_global_load_lds(
        (const __attribute__((address_space(1))) void*)g,
        (__attribute__((address_space(3))) void*)l, 16, 0, 0);
}

// Compute one staged chunk (fp32 in LDS, source-side XOR swizzle).
// A = W (bf16 regs), B = x (LDS fp32 -> cvt bf16).
// D lane map (m89): col(l15) = x-row, row(lq*4+r) = out col -> float4 stores.
template<int FIN, bool GUARD>
__device__ __forceinline__ void compute_chunk(
    const char* __restrict__ base, const bf16x8 (&Wf)[FIN/32][2],
    const f32x4 (&bv)[2], float* __restrict__ out, int nrows, int chunk,
    int l15, int lq, int colbase)
{
    constexpr int ROWS = 4096 / FIN;
    constexpr int NC   = FIN / 32;
    constexpr int MT   = ROWS / 16;
    constexpr int R    = FIN / 4;      // 16B granules per row
    #pragma unroll
    for (int mt = 0; mt < MT; ++mt) {
        const int row = mt * 16 + l15;
        const int swz = row & 7;
        f32x4 acc0 = {0.f, 0.f, 0.f, 0.f};
        f32x4 acc1 = {0.f, 0.f, 0.f, 0.f};
        #pragma unroll
        for (int c = 0; c < NC; ++c) {
            const int g0 = row * R + c * 8 + lq * 2;
            const f32x4 lo = *(const f32x4*)(base + (size_t)((g0 ^ swz) << 4));
            const f32x4 hi = *(const f32x4*)(base + (size_t)(((g0 + 1) ^ swz) << 4));
            bf16x8 xf;
            xf[0]=(__bf16)lo[0]; xf[1]=(__bf16)lo[1]; xf[2]=(__bf16)lo[2]; xf[3]=(__bf16)lo[3];
            xf[4]=(__bf16)hi[0]; xf[5]=(__bf16)hi[1]; xf[6]=(__bf16)hi[2]; xf[7]=(__bf16)hi[3];
            acc0 = __builtin_amdgcn_mfma_f32_16x16x32_bf16(Wf[c][0], xf, acc0, 0, 0, 0);
            acc1 = __builtin_amdgcn_mfma_f32_16x16x32_bf16(Wf[c][1], xf, acc1, 0, 0, 0);
        }
        const int xrow = chunk * ROWS + mt * 16 + l15;
        if (!GUARD || xrow < nrows) {
            float* op = out + (size_t)xrow * 128 + colbase;
            *(f32x4*)(op + lq * 4)      = acc0 + bv[0];
            *(f32x4*)(op + 16 + lq * 4) = acc1 + bv[1];
        }
    }
}

// Producer/consumer split: waves 0-3 stage (DMA only), waves 4-7 compute
// (stores only). 4 buffers, chunk k -> slot k%4, DEPTH-3 prefetch.
// Producer per chunk: 4 gload_lds16; steady vmcnt(8) => chunk k+1 verified,
// k+2,k+3 in flight (8-12 KB/wave outstanding). Past-the-end iterations
// re-issue 'last' (dummy) into rotating slots never read again.
template<int FIN>
__device__ __forceinline__ void run_type(
    const float* __restrict__ x, const float* __restrict__ W,
    const float* __restrict__ bias, float* __restrict__ out,
    int nrows, int c0, int c1, bool tail, float* __restrict__ lds)
{
    constexpr int ROWS = 4096 / FIN;
    constexpr int NC   = FIN / 32;
    constexpr int R    = FIN / 4;
    constexpr int LOGR = (FIN == 256) ? 6 : ((FIN == 128) ? 5 : 4);

    const int tid  = threadIdx.x;
    const int lane = tid & 63;
    const int wave = tid >> 6;
    const int l15  = lane & 15;
    const int lq   = lane >> 4;
    const bool is_prod = (wave < 4);

    const int L    = c1 - c0;
    const int last = c1 - 1;

    if (is_prod) {
        // ---------------- producer: DMA issue loop, load-only vmcnt ----------
        const int pw = wave;
        auto issue = [&](int chunk, int slot) {
            const float* src = x + (size_t)chunk * ROWS * FIN;
            #pragma unroll
            for (int i = 0; i < 4; ++i) {
                const int G   = pw * 256 + i * 64 + lane;
                const int row = G >> LOGR;
                const int kq  = (G & (R - 1)) ^ (row & 7);
                gload_lds16(src + (size_t)row * FIN + kq * 4,
                            (char*)lds + (size_t)slot * 16384 + pw * 4096 + i * 1024);
            }
        };
        if (L > 0) {
            issue(c0, c0 & 3);
            int ch1 = c0 + 1; if (ch1 > last) ch1 = last;
            issue(ch1, (c0 + 1) & 3);
            int ch2 = c0 + 2; if (ch2 > last) ch2 = last;
            issue(ch2, (c0 + 2) & 3);
            prod_wait_bar();                       // chunk c0 verified
            for (int k = c0; k < c1; ++k) {
                int ch = k + 3; if (ch > last) ch = last;
                issue(ch, (k + 3) & 3);
                prod_wait_bar();                   // chunk k+1 verified
            }
        }
    } else {
        // ---------------- consumer: compute loop, store-only queue ----------
        const int colbase = (wave - 4) * 32;
        bf16x8 Wf[NC][2];
        f32x4  bv[2];
        #pragma unroll
        for (int t = 0; t < 2; ++t) {
            const int o = colbase + t * 16 + l15;
            #pragma unroll
            for (int c = 0; c < NC; ++c) {
                const f32x4 w0 = *(const f32x4*)(W + (size_t)o * FIN + c * 32 + lq * 8);
                const f32x4 w1 = *(const f32x4*)(W + (size_t)o * FIN + c * 32 + lq * 8 + 4);
                bf16x8 fr;
                fr[0]=(__bf16)w0[0]; fr[1]=(__bf16)w0[1]; fr[2]=(__bf16)w0[2]; fr[3]=(__bf16)w0[3];
                fr[4]=(__bf16)w1[0]; fr[5]=(__bf16)w1[1]; fr[6]=(__bf16)w1[2]; fr[7]=(__bf16)w1[3];
                Wf[c][t] = fr;
            }
            bv[t] = *(const f32x4*)(bias + colbase + t * 16 + lq * 4);
        }
        if (L > 0) {
            cons_bar();                            // matches producer prologue
            for (int k = c0; k < c1; ++k) {
                compute_chunk<FIN, false>(
                    (const char*)lds + (size_t)(k & 3) * 16384,
                    Wf, bv, out, nrows, k, l15, lq, colbase);
                cons_bar();                        // matches producer loop bar
            }
        }
    }

    if (tail) {
        __syncthreads();              // drains producer DMAs (incl. dummies)
        const int pc = c1;            // partial chunk index
        #pragma unroll
        for (int i = 0; i < 2; ++i) {
            const int G   = tid + i * 512;
            const int row = G >> LOGR;
            const int kq  = (G & (R - 1)) ^ (row & 7);
            const int grow = pc * ROWS + row;
            if (grow < nrows) {
                const f32x4 v = *(const f32x4*)(x + (size_t)grow * FIN + kq * 4);
                *(f32x4*)((char*)lds + (size_t)G * 16) = v;
            }
        }
        __syncthreads();
        if (!is_prod) {
            const int colbase = (wave - 4) * 32;
            bf16x8 Wf[NC][2];
            f32x4  bv[2];
            #pragma unroll
            for (int t = 0; t < 2; ++t) {
                const int o = colbase + t * 16 + l15;
                #pragma unroll
                for (int c = 0; c < NC; ++c) {
                    const f32x4 w0 = *(const f32x4*)(W + (size_t)o * FIN + c * 32 + lq * 8);
                    const f32x4 w1 = *(const f32x4*)(W + (size_t)o * FIN + c * 32 + lq * 8 + 4);
                    bf16x8 fr;
                    fr[0]=(__bf16)w0[0]; fr[1]=(__bf16)w0[1]; fr[2]=(__bf16)w0[2]; fr[3]=(__bf16)w0[3];
                    fr[4]=(__bf16)w1[0]; fr[5]=(__bf16)w1[1]; fr[6]=(__bf16)w1[2]; fr[7]=(__bf16)w1[3];
                    Wf[c][t] = fr;
                }
                bv[t] = *(const f32x4*)(bias + colbase + t * 16 + lq * 4);
            }
            compute_chunk<FIN, true>((const char*)lds, Wf, bv, out, nrows, pc,
                                     l15, lq, colbase);
        }
    }
}

__global__ __launch_bounds__(512, 4) void hetero_fused_kern(KArgs A)
{
    __shared__ float lds[4 * 4096];   // 64 KiB: quad buffer (depth-3 prefetch)

    int ty = 0;
    const int bid = blockIdx.x;
    while (ty < 5 && bid >= A.blk0[ty + 1]) ++ty;
    const int lb = bid - A.blk0[ty];
    const int nb = A.blk0[ty + 1] - A.blk0[ty];

    const int nrows = A.nrows[ty];
    const int ROWS  = (ty == 1) ? 16 : ((ty == 2 || ty == 4) ? 64 : 32);
    const int F     = nrows / ROWS;
    const bool part = (nrows % ROWS) != 0;
    const int c0 = (int)(((long)F * lb) / nb);
    const int c1 = (int)(((long)F * (lb + 1)) / nb);
    const bool tail = part && (lb == nb - 1);

    switch (ty) {
        case 0: run_type<128>(A.x[0], A.W[0], A.b[0], A.out[0], nrows, c0, c1, tail, lds); break;
        case 1: run_type<256>(A.x[1], A.W[1], A.b[1], A.out[1], nrows, c0, c1, tail, lds); break;
        case 2: run_type< 64>(A.x[2], A.W[2], A.b[2], A.out[2], nrows, c0, c1, tail, lds); break;
        case 3: run_type<128>(A.x[3], A.W[3], A.b[3], A.out[3], nrows, c0, c1, tail, lds); break;
        case 4: run_type< 64>(A.x[4], A.W[4], A.b[4], A.out[4], nrows, c0, c1, tail, lds); break;
        case 5: run_type<128>(A.x[5], A.W[5], A.b[5], A.out[5], nrows, c0, c1, tail, lds); break;
    }
}

extern "C" void kernel_launch(void* const* d_in, const int* in_sizes, int n_in,
                              void* d_out, int out_size, void* d_ws, size_t ws_size,
                              hipStream_t stream)
{
    float* out = (float*)d_out;
    KArgs A;
    // 0 author(100000,128) 1 paper(250000,256) 2 venue(25000,64)
    // 3 institution(50000,128) 4 field(75000,64) 5 term(150000,128)
    const int  nrows[6] = {100000, 250000, 25000, 50000, 75000, 150000};
    const long ooff[6]  = {0L, 12800000L, 44800000L, 48000000L, 54400000L, 64000000L};
    // 1024 blocks of 512 threads (2 blocks/CU); bytes-proportional split
    const int  blk0[7]  = {0, 137, 649, 674, 742, 819, 1024};
    for (int t = 0; t < 6; ++t) {
        A.x[t]     = (const float*)d_in[3 * t + 0];
        A.W[t]     = (const float*)d_in[3 * t + 1];
        A.b[t]     = (const float*)d_in[3 * t + 2];
        A.out[t]   = out + ooff[t];
        A.nrows[t] = nrows[t];
    }
    for (int i = 0; i < 7; ++i) A.blk0[i] = blk0[i];

    hetero_fused_kern<<<1024, 512, 0, stream>>>(A);
}

// Round 14
// 158.733 us; speedup vs baseline: 1.0083x; 1.0083x over previous
//
#include <hip/hip_runtime.h>

typedef __bf16 bf16x8 __attribute__((ext_vector_type(8)));
typedef float  f32x4  __attribute__((ext_vector_type(4)));

struct KArgs {
    const float* x[6];
    const float* W[6];
    const float* b[6];
    float*       out[6];
    int nrows[6];
    int blk0[7];
};

// producer: counted load-only wait fused with barrier (queue has ONLY DMAs)
__device__ __forceinline__ void prod_wait_bar() {
    asm volatile("s_waitcnt vmcnt(4)\n\ts_barrier" ::: "memory");
}
// consumer: lgkm-only barrier (its vmem queue = stores; never waited)
__device__ __forceinline__ void cons_bar() {
    asm volatile("s_waitcnt lgkmcnt(0)\n\ts_barrier" ::: "memory");
}

__device__ __forceinline__ void gload_lds16(const float* g, void* l) {
    __builtin_amdgcn_global_load_lds(
        (const __attribute__((address_space(1))) void*)g,
        (__attribute__((address_space(3))) void*)l, 16, 0, 0);
}

// Compute one staged chunk (fp32 in LDS, source-side XOR swizzle).
// A = W (bf16 regs), B = x (LDS fp32 -> cvt bf16).
// D lane map (m89): col(l15) = x-row, row(lq*4+r) = out col -> float4 stores.
template<int FIN, bool GUARD>
__device__ __forceinline__ void compute_chunk(
    const char* __restrict__ base, const bf16x8 (&Wf)[FIN/32][2],
    const f32x4 (&bv)[2], float* __restrict__ out, int nrows, int chunk,
    int l15, int lq, int colbase)
{
    constexpr int ROWS = 4096 / FIN;
    constexpr int NC   = FIN / 32;
    constexpr int MT   = ROWS / 16;
    constexpr int R    = FIN / 4;      // 16B granules per row
    #pragma unroll
    for (int mt = 0; mt < MT; ++mt) {
        const int row = mt * 16 + l15;
        const int swz = row & 7;
        f32x4 acc0 = {0.f, 0.f, 0.f, 0.f};
        f32x4 acc1 = {0.f, 0.f, 0.f, 0.f};
        #pragma unroll
        for (int c = 0; c < NC; ++c) {
            const int g0 = row * R + c * 8 + lq * 2;
            const f32x4 lo = *(const f32x4*)(base + (size_t)((g0 ^ swz) << 4));
            const f32x4 hi = *(const f32x4*)(base + (size_t)(((g0 + 1) ^ swz) << 4));
            bf16x8 xf;
            xf[0]=(__bf16)lo[0]; xf[1]=(__bf16)lo[1]; xf[2]=(__bf16)lo[2]; xf[3]=(__bf16)lo[3];
            xf[4]=(__bf16)hi[0]; xf[5]=(__bf16)hi[1]; xf[6]=(__bf16)hi[2]; xf[7]=(__bf16)hi[3];
            acc0 = __builtin_amdgcn_mfma_f32_16x16x32_bf16(Wf[c][0], xf, acc0, 0, 0, 0);
            acc1 = __builtin_amdgcn_mfma_f32_16x16x32_bf16(Wf[c][1], xf, acc1, 0, 0, 0);
        }
        const int xrow = chunk * ROWS + mt * 16 + l15;
        if (!GUARD || xrow < nrows) {
            float* op = out + (size_t)xrow * 128 + colbase;
            *(f32x4*)(op + lq * 4)      = acc0 + bv[0];
            *(f32x4*)(op + 16 + lq * 4) = acc1 + bv[1];
        }
    }
}

// Producer/consumer split: waves 0-3 stage (DMA only), waves 4-7 compute
// (stores only). 3 buffers, chunk k -> slot k%3, depth-2 prefetch.
template<int FIN>
__device__ __forceinline__ void run_type(
    const float* __restrict__ x, const float* __restrict__ W,
    const float* __restrict__ bias, float* __restrict__ out,
    int nrows, int c0, int c1, bool tail, float* __restrict__ lds)
{
    constexpr int ROWS = 4096 / FIN;
    constexpr int NC   = FIN / 32;
    constexpr int R    = FIN / 4;
    constexpr int LOGR = (FIN == 256) ? 6 : ((FIN == 128) ? 5 : 4);

    const int tid  = threadIdx.x;
    const int lane = tid & 63;
    const int wave = tid >> 6;
    const int l15  = lane & 15;
    const int lq   = lane >> 4;
    const bool is_prod = (wave < 4);

    const int L    = c1 - c0;
    const int last = c1 - 1;

    if (is_prod) {
        // ---------------- producer: DMA issue loop, load-only vmcnt ----------
        const int pw = wave;
        auto issue = [&](int chunk, int slot) {
            const float* src = x + (size_t)chunk * ROWS * FIN;
            #pragma unroll
            for (int i = 0; i < 4; ++i) {
                const int G   = pw * 256 + i * 64 + lane;
                const int row = G >> LOGR;
                const int kq  = (G & (R - 1)) ^ (row & 7);
                gload_lds16(src + (size_t)row * FIN + kq * 4,
                            (char*)lds + (size_t)slot * 16384 + pw * 4096 + i * 1024);
            }
        };
        if (L > 0) {
            issue(c0, c0 % 3);
            int ch1 = c0 + 1; if (ch1 > last) ch1 = last;
            issue(ch1, (c0 + 1) % 3);
            prod_wait_bar();                       // chunk c0 verified
            for (int k = c0; k < c1; ++k) {
                int ch = k + 2; if (ch > last) ch = last;
                issue(ch, (k + 2) % 3);
                prod_wait_bar();                   // chunk k+1 verified
            }
        }
    } else {
        // ---------------- consumer: compute loop, store-only queue ----------
        const int colbase = (wave - 4) * 32;
        bf16x8 Wf[NC][2];
        f32x4  bv[2];
        #pragma unroll
        for (int t = 0; t < 2; ++t) {
            const int o = colbase + t * 16 + l15;
            #pragma unroll
            for (int c = 0; c < NC; ++c) {
                const f32x4 w0 = *(const f32x4*)(W + (size_t)o * FIN + c * 32 + lq * 8);
                const f32x4 w1 = *(const f32x4*)(W + (size_t)o * FIN + c * 32 + lq * 8 + 4);
                bf16x8 fr;
                fr[0]=(__bf16)w0[0]; fr[1]=(__bf16)w0[1]; fr[2]=(__bf16)w0[2]; fr[3]=(__bf16)w0[3];
                fr[4]=(__bf16)w1[0]; fr[5]=(__bf16)w1[1]; fr[6]=(__bf16)w1[2]; fr[7]=(__bf16)w1[3];
                Wf[c][t] = fr;
            }
            bv[t] = *(const f32x4*)(bias + colbase + t * 16 + lq * 4);
        }
        if (L > 0) {
            cons_bar();                            // matches producer prologue
            for (int k = c0; k < c1; ++k) {
                compute_chunk<FIN, false>(
                    (const char*)lds + (size_t)(k % 3) * 16384,
                    Wf, bv, out, nrows, k, l15, lq, colbase);
                cons_bar();                        // matches producer loop bar
            }
        }
    }

    if (tail) {
        __syncthreads();              // drains producer DMAs (incl. dummies)
        const int pc = c1;            // partial chunk index
        #pragma unroll
        for (int i = 0; i < 2; ++i) {
            const int G   = tid + i * 512;
            const int row = G >> LOGR;
            const int kq  = (G & (R - 1)) ^ (row & 7);
            const int grow = pc * ROWS + row;
            if (grow < nrows) {
                const f32x4 v = *(const f32x4*)(x + (size_t)grow * FIN + kq * 4);
                *(f32x4*)((char*)lds + (size_t)G * 16) = v;
            }
        }
        __syncthreads();
        if (!is_prod) {
            const int colbase = (wave - 4) * 32;
            bf16x8 Wf[NC][2];
            f32x4  bv[2];
            #pragma unroll
            for (int t = 0; t < 2; ++t) {
                const int o = colbase + t * 16 + l15;
                #pragma unroll
                for (int c = 0; c < NC; ++c) {
                    const f32x4 w0 = *(const f32x4*)(W + (size_t)o * FIN + c * 32 + lq * 8);
                    const f32x4 w1 = *(const f32x4*)(W + (size_t)o * FIN + c * 32 + lq * 8 + 4);
                    bf16x8 fr;
                    fr[0]=(__bf16)w0[0]; fr[1]=(__bf16)w0[1]; fr[2]=(__bf16)w0[2]; fr[3]=(__bf16)w0[3];
                    fr[4]=(__bf16)w1[0]; fr[5]=(__bf16)w1[1]; fr[6]=(__bf16)w1[2]; fr[7]=(__bf16)w1[3];
                    Wf[c][t] = fr;
                }
                bv[t] = *(const f32x4*)(bias + colbase + t * 16 + lq * 4);
            }
            compute_chunk<FIN, true>((const char*)lds, Wf, bv, out, nrows, pc,
                                     l15, lq, colbase);
        }
    }
}

__global__ __launch_bounds__(512, 4) void hetero_fused_kern(KArgs A)
{
    __shared__ float lds[3 * 4096];   // 48 KiB triple buffer

    int ty = 0;
    const int bid = blockIdx.x;
    while (ty < 5 && bid >= A.blk0[ty + 1]) ++ty;
    const int lb = bid - A.blk0[ty];
    const int nb = A.blk0[ty + 1] - A.blk0[ty];

    const int nrows = A.nrows[ty];
    const int ROWS  = (ty == 1) ? 16 : ((ty == 2 || ty == 4) ? 64 : 32);
    const int F     = nrows / ROWS;
    const bool part = (nrows % ROWS) != 0;
    const int c0 = (int)(((long)F * lb) / nb);
    const int c1 = (int)(((long)F * (lb + 1)) / nb);
    const bool tail = part && (lb == nb - 1);

    switch (ty) {
        case 0: run_type<128>(A.x[0], A.W[0], A.b[0], A.out[0], nrows, c0, c1, tail, lds); break;
        case 1: run_type<256>(A.x[1], A.W[1], A.b[1], A.out[1], nrows, c0, c1, tail, lds); break;
        case 2: run_type< 64>(A.x[2], A.W[2], A.b[2], A.out[2], nrows, c0, c1, tail, lds); break;
        case 3: run_type<128>(A.x[3], A.W[3], A.b[3], A.out[3], nrows, c0, c1, tail, lds); break;
        case 4: run_type< 64>(A.x[4], A.W[4], A.b[4], A.out[4], nrows, c0, c1, tail, lds); break;
        case 5: run_type<128>(A.x[5], A.W[5], A.b[5], A.out[5], nrows, c0, c1, tail, lds); break;
    }
}

extern "C" void kernel_launch(void* const* d_in, const int* in_sizes, int n_in,
                              void* d_out, int out_size, void* d_ws, size_t ws_size,
                              hipStream_t stream)
{
    float* out = (float*)d_out;
    KArgs A;
    // 0 author(100000,128) 1 paper(250000,256) 2 venue(25000,64)
    // 3 institution(50000,128) 4 field(75000,64) 5 term(150000,128)
    const int  nrows[6] = {100000, 250000, 25000, 50000, 75000, 150000};
    const long ooff[6]  = {0L, 12800000L, 44800000L, 48000000L, 54400000L, 64000000L};
    // 1536 blocks (3 residency rounds of 512 -> retire/backfill smoothing);
    // bytes-proportional split, same proportions as R12.
    const int  blk0[7]  = {0, 205, 973, 1011, 1113, 1228, 1536};
    for (int t = 0; t < 6; ++t) {
        A.x[t]     = (const float*)d_in[3 * t + 0];
        A.W[t]     = (const float*)d_in[3 * t + 1];
        A.b[t]     = (const float*)d_in[3 * t + 2];
        A.out[t]   = out + ooff[t];
        A.nrows[t] = nrows[t];
    }
    for (int i = 0; i < 7; ++i) A.blk0[i] = blk0[i];

    hetero_fused_kern<<<1536, 512, 0, stream>>>(A);
}